// Round 12
// baseline (435.973 us; speedup 1.0000x reference)
//
#include <hip/hip_runtime.h>
#include <hip/hip_bf16.h>

// RNN-T joint network. B=4 T=256 U=64 D=512 J=512 V=1024.
//   Pe = enc @ W_enc^T + b_enc   (1024 x 512)  fp32 in ws
//   Pd = dec @ W_dec^T           (256  x 512)  fp32 in ws
//   out[m,:] = tanh(Pe[m>>6] + Pd[(m>>14)*64 + (m&63)]) @ W_out^T + b_out
//
// gemm_joint (round-12): faithful m201 8-phase port (T3+T4+T5), A fused
// via T14 reg-staging.
//   R3/R5/R7/R10/R11 all converge ~170-176us regardless of staging detail:
//   the shared flaw is ONE barrier-pair per K-step with ~130cy MFMA between
//   (m233: 2-phase = 72% structural stall). m201's fix: 4 phases/K-tile,
//   stages SPREAD across phases, counted vmcnt once per tile, 2 barriers
//   per small phase -- 62% MfmaUtil at 1 WG/CU (occupancy not the lever).
// Geometry: BM=BN=256, BK=64, 1024 blocks, 512 thr / 8 waves (2M x 4N),
// wave-tile 128x64, acc[4][2] f32x16 (128 VGPR), 32x32x16 MFMA.
// LDS 128KB: sA/sB = 2 x 32KB each, chunk-major [c][row][8] (the layout
// family measured 0-conflict in R9-R11 for reads, writes, and DMA dests).
// Per K-tile t (buf b=t&1): P0 issue 16 A-loads(t+1); P1/P2 issue 2+2
// B-gload_lds(t+1 -> b^1, WT coalesced); P3: vmcnt(4) (= drain exactly the
// 16 A-loads, keep 4 B-DMAs in flight), tanh -> 4 ds_write(b^1), MFMA,
// then vmcnt(0) before the end barrier. Each phase: reads; barrier;
// lgkmcnt(0); setprio(1); 8 MFMA; setprio(0); barrier  (m201 discipline,
// rule-18 sched_barrier(0) after every asm wait).

typedef __attribute__((ext_vector_type(8))) short short8;     // 8 bf16
typedef __attribute__((ext_vector_type(4))) float f32x4;
typedef __attribute__((ext_vector_type(16))) float f32x16;

#define SZ0 524288
#define SZ1 131072
#define SZ2 262144
#define SZ3 512
#define SZ4 262144
#define SZ5 524288
#define SZ6 1024
#define CU0 0
#define CU1 524288
#define CU2 655360
#define CU3 917504
#define CU4 918016
#define CU5 1180160
#define CU6 1704448
#define CTOT 1705472

// ---------------------------------------------------------------------------
// Runtime dtype detection (unchanged).
// ---------------------------------------------------------------------------
__global__ void detect_kernel(const void* p0, const void* p1, const void* p2,
                              const void* p3, const void* p4, const void* p5,
                              const void* p6, int* flags) {
  const void* ps[7] = {p0, p1, p2, p3, p4, p5, p6};
  const int sz[7] = {SZ0, SZ1, SZ2, SZ3, SZ4, SZ5, SZ6};
  const int w = threadIdx.x >> 6;
  const int l = threadIdx.x & 63;
  if (w >= 7) return;
  const unsigned short* u = (const unsigned short*)ps[w];
  const int lim = sz[w] < 1024 ? sz[w] : 1024;
  int bad = 0;
  for (int j = l; j < lim; j += 64) {
    const unsigned e = (u[j] >> 7) & 0xFFu;
    if (e >= 0x8Eu) bad = 1;
  }
  const unsigned long long b = __ballot(bad);
  if (l == 0) flags[w] = (b != 0ULL) ? 1 : 0;
}

__global__ __launch_bounds__(256) void convert_kernel(
    const void* p0, const void* p1, const void* p2, const void* p3,
    const void* p4, const void* p5, const void* p6,
    const int* __restrict__ flags, __hip_bfloat16* __restrict__ dst) {
  const int gid = blockIdx.x * 256 + threadIdx.x;
  if (gid >= CTOT) return;
  int t, local;
  const void* p;
  if (gid < CU1)      { t = 0; local = gid - CU0; p = p0; }
  else if (gid < CU2) { t = 1; local = gid - CU1; p = p1; }
  else if (gid < CU3) { t = 2; local = gid - CU2; p = p2; }
  else if (gid < CU4) { t = 3; local = gid - CU3; p = p3; }
  else if (gid < CU5) { t = 4; local = gid - CU4; p = p4; }
  else if (gid < CU6) { t = 5; local = gid - CU5; p = p5; }
  else                { t = 6; local = gid - CU6; p = p6; }
  __hip_bfloat16 v;
  if (flags[t])
    v = __float2bfloat16(((const float*)p)[local]);
  else
    v = ((const __hip_bfloat16*)p)[local];
  dst[gid] = v;
}

// ---------------------------------------------------------------------------
// m97-structure GEMM body for the two small projections (unchanged).
// ---------------------------------------------------------------------------
__device__ __forceinline__ void gemm_bt_body(
    const __hip_bfloat16* __restrict__ A, const __hip_bfloat16* __restrict__ Bw,
    const __hip_bfloat16* __restrict__ bias, float* __restrict__ C,
    int M, int N, int K, int bid,
    __hip_bfloat16* sA, __hip_bfloat16* sB) {
  const int tid = threadIdx.x;
  const int w = tid >> 6;
  const int l = tid & 63;
  const int ntiles = N >> 7;
  const int mt = bid / ntiles;
  const int nt = bid % ntiles;
  const int m0 = mt << 7;
  const int n0 = nt << 7;
  const int wm = (w >> 1) << 6;
  const int wn = (w & 1) << 6;
  const int r16 = l & 15;
  const int q = l >> 4;

  f32x4 acc[4][4] = {};

  const int srow_in = l >> 3;
  const int scol = (l & 7) << 3;

  for (int k0 = 0; k0 < K; k0 += 64) {
#pragma unroll
    for (int i = 0; i < 4; ++i) {
      const int c = (w << 2) + i;
      const int row = (c << 3) + srow_in;
      const __hip_bfloat16* gA = A + (size_t)(m0 + row) * K + k0 + scol;
      const __hip_bfloat16* gB = Bw + (size_t)(n0 + row) * K + k0 + scol;
      __builtin_amdgcn_global_load_lds(
          (const __attribute__((address_space(1))) void*)gA,
          (__attribute__((address_space(3))) void*)(sA + (c << 9) + (l << 3)),
          16, 0, 0);
      __builtin_amdgcn_global_load_lds(
          (const __attribute__((address_space(1))) void*)gB,
          (__attribute__((address_space(3))) void*)(sB + (c << 9) + (l << 3)),
          16, 0, 0);
    }
    __syncthreads();

#pragma unroll
    for (int kk = 0; kk < 2; ++kk) {
      const int kc = (kk << 5) + (q << 3);
      short8 af[4], bf[4];
#pragma unroll
      for (int mi = 0; mi < 4; ++mi)
        af[mi] = *(const short8*)(sA + (wm + (mi << 4) + r16) * 64 + kc);
#pragma unroll
      for (int ni = 0; ni < 4; ++ni)
        bf[ni] = *(const short8*)(sB + (wn + (ni << 4) + r16) * 64 + kc);
#pragma unroll
      for (int mi = 0; mi < 4; ++mi)
#pragma unroll
        for (int ni = 0; ni < 4; ++ni)
          acc[mi][ni] = __builtin_amdgcn_mfma_f32_16x16x32_bf16(
              af[mi], bf[ni], acc[mi][ni], 0, 0, 0);
    }
    __syncthreads();
  }

#pragma unroll
  for (int ni = 0; ni < 4; ++ni) {
    const int col = n0 + wn + (ni << 4) + r16;
    const float bc = bias ? __bfloat162float(bias[col]) : 0.0f;
#pragma unroll
    for (int mi = 0; mi < 4; ++mi) {
      const int rowb = m0 + wm + (mi << 4) + (q << 2);
#pragma unroll
      for (int i = 0; i < 4; ++i)
        C[(size_t)(rowb + i) * N + col] = acc[mi][ni][i] + bc;
    }
  }
}

// proj blocks 0..39: Pe/Pd GEMMs. Blocks 40..47: W_out -> WT transpose,
// WT[(k>>3)*1024 + n][8] = W_out[n][k&~7 .. +8]  (chunk-major, 1MB).
__global__ __launch_bounds__(256) void proj_kernel(
    const __hip_bfloat16* __restrict__ enc, const __hip_bfloat16* __restrict__ Wenc,
    const __hip_bfloat16* __restrict__ benc,
    const __hip_bfloat16* __restrict__ dec, const __hip_bfloat16* __restrict__ Wdec,
    const __hip_bfloat16* __restrict__ Wout, __hip_bfloat16* __restrict__ WT,
    float* __restrict__ Pe, float* __restrict__ Pd) {
  __shared__ __align__(16) __hip_bfloat16 sA[128 * 64];
  __shared__ __align__(16) __hip_bfloat16 sB[128 * 64];
  if (blockIdx.x < 32) {
    gemm_bt_body(enc, Wenc, benc, Pe, 1024, 512, 512, blockIdx.x, sA, sB);
  } else if (blockIdx.x < 40) {
    gemm_bt_body(dec, Wdec, nullptr, Pd, 256, 512, 512, blockIdx.x - 32, sA, sB);
  } else {
    const int bid = blockIdx.x - 40;            // 0..7
#pragma unroll
    for (int i = 0; i < 32; ++i) {
      const int cid = (bid << 13) + (i << 8) + threadIdx.x;  // 0..65535
      const int n = cid >> 6;
      const int c = cid & 63;
      *(short8*)(WT + (((size_t)c << 10) + n) * 8) =
          *(const short8*)(Wout + (size_t)n * 512 + (c << 3));
    }
  }
}

// ---------------------------------------------------------------------------
// Main fused GEMM, m201 8-phase schedule. grid = 1024 (256 mb x 4 nb),
// 512 threads / 8 waves (2M x 4N), wave-tile 128x64, acc[4][2] f32x16.
// LDS 128KB: sA[2][8c][256r][8] + sB[2][8c][256n][8] (chunk-major).
// K = 512 = 8 K-tiles of 64; 4 phases per K-tile (one k-step of 16 each).
// ---------------------------------------------------------------------------
__global__ __launch_bounds__(512, 2) void gemm_joint(
    const float* __restrict__ Pe, const float* __restrict__ Pd,
    const __hip_bfloat16* __restrict__ WT,
    const __hip_bfloat16* __restrict__ bias, float* __restrict__ out) {
  __shared__ __align__(16) __hip_bfloat16 sA[2][2048 * 8];  // 2 x 32 KB
  __shared__ __align__(16) __hip_bfloat16 sB[2][2048 * 8];  // 2 x 32 KB

  const int t = threadIdx.x;
  const int w = t >> 6;
  const int l = t & 63;
  const int l31 = l & 31;
  const int q2 = l >> 5;
  const int mb = blockIdx.x >> 2;
  const int nb = blockIdx.x & 3;
  const int m0 = mb << 8;
  const int n0 = nb << 8;
  const int wm = (w >> 2) << 7;   // 0 or 128
  const int wn = (w & 3) << 6;    // 0,64,128,192

  // A-slot ownership: thread t covers row arow = t&255, chunks acb..acb+3.
  const int arow = t & 255;
  const int acb = (t >> 8) << 2;
  const int e = (mb << 2) + (arow >> 6);                 // Pe row (wave-uniform)
  const int dd = ((mb >> 6) << 6) | (arow & 63);         // Pd row

  // A-loads for tile kt -> regs (exactly 16 dwordx4: vmcnt count = 16).
  f32x4 rPe[4][2], rPd[4][2];
  auto issueA = [&](int kt) {
    const float* peR = Pe + (size_t)e * 512 + (kt << 6);
    const float* pdR = Pd + (size_t)dd * 512 + (kt << 6);
#pragma unroll
    for (int j = 0; j < 4; ++j) {
      const int off = (acb + j) << 3;
      rPe[j][0] = *(const f32x4*)(peR + off);
      rPe[j][1] = *(const f32x4*)(peR + off + 4);
      rPd[j][0] = *(const f32x4*)(pdR + off);
      rPd[j][1] = *(const f32x4*)(pdR + off + 4);
    }
  };

  // tanh(A) -> sA[b], chunk-major, ds_write lane-consecutive 16B.
  auto writeA = [&](int b) {
#pragma unroll
    for (int j = 0; j < 4; ++j) {
      short8 hv;
#pragma unroll
      for (int x = 0; x < 4; ++x) {
        float sv = rPe[j][0][x] + rPd[j][0][x];
        float u = __expf(2.0f * sv);
        float tv = 1.0f - 2.0f * __builtin_amdgcn_rcpf(u + 1.0f);
        __hip_bfloat16 hb = __float2bfloat16(tv);
        hv[x] = *(const short*)&hb;
        sv = rPe[j][1][x] + rPd[j][1][x];
        u = __expf(2.0f * sv);
        tv = 1.0f - 2.0f * __builtin_amdgcn_rcpf(u + 1.0f);
        hb = __float2bfloat16(tv);
        hv[4 + x] = *(const short*)&hb;
      }
      *(short8*)(&sA[b][0] + ((((acb + j) << 8) + arow) << 3)) = hv;
    }
  };

  // One B-DMA instruction: slot = h*512+t; c = slot>>8, n = slot&255.
  // WT source: 64 consecutive lanes = 1KB contiguous. Dest uniform+l*16.
  auto issueB = [&](int kt, int b, int h) {
    const int slot = (h << 9) + t;
    const int c = slot >> 8;
    const int n = slot & 255;
    const __hip_bfloat16* src =
        WT + (((size_t)((kt << 3) + c) << 10) + n0 + n) * 8;
    __builtin_amdgcn_global_load_lds(
        (const __attribute__((address_space(1))) void*)src,
        (__attribute__((address_space(3))) void*)(&sB[b][0] + (slot << 3)),
        16, 0, 0);
  };

  // Prologue: tile 0 fully staged (A regs -> tanh -> LDS; B via DMA).
  issueA(0);
#pragma unroll
  for (int h = 0; h < 4; ++h) issueB(0, 0, h);
  asm volatile("s_waitcnt vmcnt(4)" ::: "memory");   // 16 A-loads done
  __builtin_amdgcn_sched_barrier(0);
  writeA(0);
  asm volatile("s_waitcnt lgkmcnt(0) vmcnt(0)" ::: "memory");
  __builtin_amdgcn_sched_barrier(0);
  __builtin_amdgcn_s_barrier();
  __builtin_amdgcn_sched_barrier(0);

  f32x16 acc[4][2] = {};

#define READS(s)                                                             \
  {                                                                          \
    const int c = ((s) << 1) + q2;                                           \
    _Pragma("unroll") for (int mi = 0; mi < 4; ++mi) af[mi] =                \
        *(const short8*)(&sA[b][0] +                                         \
                         (((c << 8) + wm + (mi << 5) + l31) << 3));          \
    _Pragma("unroll") for (int ni = 0; ni < 2; ++ni) bf[ni] =                \
        *(const short8*)(&sB[b][0] +                                         \
                         (((c << 8) + wn + (ni << 5) + l31) << 3));          \
  }
#define MFMA8                                                                \
  _Pragma("unroll") for (int mi = 0; mi < 4; ++mi)                           \
      _Pragma("unroll") for (int ni = 0; ni < 2; ++ni) acc[mi][ni] =         \
          __builtin_amdgcn_mfma_f32_32x32x16_bf16(af[mi], bf[ni],            \
                                                  acc[mi][ni], 0, 0, 0);
#define PHASE_SYNC_PRE                                                       \
  __builtin_amdgcn_s_barrier();                                              \
  asm volatile("s_waitcnt lgkmcnt(0)" ::: "memory");                         \
  __builtin_amdgcn_sched_barrier(0);                                         \
  __builtin_amdgcn_s_setprio(1);
#define PHASE_SYNC_POST                                                      \
  __builtin_amdgcn_s_setprio(0);                                             \
  __builtin_amdgcn_sched_barrier(0);                                         \
  __builtin_amdgcn_s_barrier();                                              \
  __builtin_amdgcn_sched_barrier(0);

#pragma unroll
  for (int kt = 0; kt < 8; ++kt) {
    const int b = kt & 1;
    short8 af[4], bf[2];

    // ---- phase 0: issue next tile's A-loads; k-step 0
    if (kt < 7) issueA(kt + 1);
    READS(0)
    PHASE_SYNC_PRE
    MFMA8
    PHASE_SYNC_POST

    // ---- phase 1: issue B-DMA halves 0,1; k-step 1
    if (kt < 7) { issueB(kt + 1, b ^ 1, 0); issueB(kt + 1, b ^ 1, 1); }
    READS(1)
    PHASE_SYNC_PRE
    MFMA8
    PHASE_SYNC_POST

    // ---- phase 2: issue B-DMA halves 2,3; k-step 2
    if (kt < 7) { issueB(kt + 1, b ^ 1, 2); issueB(kt + 1, b ^ 1, 3); }
    READS(2)
    PHASE_SYNC_PRE
    MFMA8
    PHASE_SYNC_POST

    // ---- phase 3: k-step 3 + tanh->ds_write(b^1) + counted drains
    READS(3)
    if (kt < 7) {
      asm volatile("s_waitcnt vmcnt(4)" ::: "memory");  // A-loads done,
      __builtin_amdgcn_sched_barrier(0);                // 4 B-DMAs in flight
      writeA(b ^ 1);
    }
    __builtin_amdgcn_s_barrier();
    asm volatile("s_waitcnt lgkmcnt(0)" ::: "memory");  // reads + A-writes
    __builtin_amdgcn_sched_barrier(0);
    __builtin_amdgcn_s_setprio(1);
    MFMA8
    __builtin_amdgcn_s_setprio(0);
    asm volatile("s_waitcnt vmcnt(0)" ::: "memory");    // B(kt+1) landed
    __builtin_amdgcn_sched_barrier(0);
    __builtin_amdgcn_s_barrier();   // publish b^1 (A writes + B DMA) to all
    __builtin_amdgcn_sched_barrier(0);
  }
#undef READS
#undef MFMA8
#undef PHASE_SYNC_PRE
#undef PHASE_SYNC_POST

  // Epilogue: C/D layout (harness-verified R4..R11):
  // col = l&31, row = (rr&3) + 8*(rr>>2) + 4*q2.
#pragma unroll
  for (int ni = 0; ni < 2; ++ni) {
    const int col = n0 + wn + (ni << 5) + l31;
    const float bc = __bfloat162float(bias[col]);
#pragma unroll
    for (int mi = 0; mi < 4; ++mi) {
#pragma unroll
      for (int rr = 0; rr < 16; ++rr) {
        const int row = m0 + wm + (mi << 5) + (rr & 3) + ((rr >> 2) << 3) +
                        (q2 << 2);
        out[(size_t)row * 1024 + col] = acc[mi][ni][rr] + bc;
      }
    }
  }
}

// ---------------------------------------------------------------------------
extern "C" void kernel_launch(void* const* d_in, const int* in_sizes, int n_in,
                              void* d_out, int out_size, void* d_ws,
                              size_t ws_size, hipStream_t stream) {
  // ws: 0 flags | 256 bf16 copies (3.41MB) | 4MB Pe (2MB) | 6MB Pd (0.5MB)
  //     | 8MB WT (1MB, chunk-transposed W_out)
  char* ws = (char*)d_ws;
  int* flags = (int*)ws;
  __hip_bfloat16* cp = (__hip_bfloat16*)(ws + 256);
  float* Pe = (float*)(ws + (4ull << 20));
  float* Pd = (float*)(ws + (6ull << 20));
  __hip_bfloat16* WT = (__hip_bfloat16*)(ws + (8ull << 20));

  detect_kernel<<<dim3(1), dim3(512), 0, stream>>>(
      d_in[0], d_in[1], d_in[2], d_in[3], d_in[4], d_in[5], d_in[6], flags);
  convert_kernel<<<dim3((CTOT + 255) / 256), dim3(256), 0, stream>>>(
      d_in[0], d_in[1], d_in[2], d_in[3], d_in[4], d_in[5], d_in[6], flags, cp);

  const __hip_bfloat16* enc_c = cp + CU0;
  const __hip_bfloat16* dec_c = cp + CU1;
  const __hip_bfloat16* Wenc_c = cp + CU2;
  const __hip_bfloat16* benc_c = cp + CU3;
  const __hip_bfloat16* Wdec_c = cp + CU4;
  const __hip_bfloat16* Wout_c = cp + CU5;
  const __hip_bfloat16* bout_c = cp + CU6;

  proj_kernel<<<dim3(48), dim3(256), 0, stream>>>(
      enc_c, Wenc_c, benc_c, dec_c, Wdec_c, Wout_c, WT, Pe, Pd);
  gemm_joint<<<dim3(1024), dim3(512), 0, stream>>>(
      Pe, Pd, WT, bout_c, (float*)d_out);
}

// Round 13
// 406.645 us; speedup vs baseline: 1.0721x; 1.0721x over previous
//
#include <hip/hip_runtime.h>
#include <hip/hip_bf16.h>

// RNN-T joint network. B=4 T=256 U=64 D=512 J=512 V=1024.
//   Pe = enc @ W_enc^T + b_enc   (1024 x 512)  fp32 in ws
//   Pd = dec @ W_dec^T           (256  x 512)  fp32 in ws  (+ PdT transposed)
//   out[m,:] = tanh(Pe[m>>6] + Pd[(m>>14)*64 + (m&63)]) @ W_out^T + b_out
//
// gemm_joint (round-13): R12's 8-phase schedule + THE GATHER FIX.
//   R12 accounting: MfmaUtil 15% x 187us = 28us = exactly the MFMA floor;
//   the other 160us is L1 line traffic: issueA's Pd loads were 2KB-stride
//   per-lane gathers (64 lines/instr, 25% line utilization) -> ~4600 lines
//   per K-tile per CU vs 512cy MFMA. Every structure R3-R12 shared this
//   A-production gather -- which is why they all converged at 150-190us.
//   Fix: PdT[k][d] pre-transpose (0.5MB fp32, written directly from the
//   Pd-GEMM epilogue). Lane l reads PdT[k*256+dbase+l]: per instruction
//   64 lanes = 256B contiguous, 4 fully-used lines (16x fewer than before).
//   A-traffic per K-tile: 4096 -> ~1100 lines. All else from R12 kept:
//   chunk-major LDS (0-conflict family), counted vmcnt, m201 phase
//   discipline, verified MFMA layouts. A-issue split over phases 0-1,
//   B-DMAs in phase 2 (so phase-3 vmcnt(4) = 4 B-DMAs still correct).

typedef __attribute__((ext_vector_type(8))) short short8;     // 8 bf16
typedef __attribute__((ext_vector_type(4))) float f32x4;
typedef __attribute__((ext_vector_type(16))) float f32x16;

#define SZ0 524288
#define SZ1 131072
#define SZ2 262144
#define SZ3 512
#define SZ4 262144
#define SZ5 524288
#define SZ6 1024
#define CU0 0
#define CU1 524288
#define CU2 655360
#define CU3 917504
#define CU4 918016
#define CU5 1180160
#define CU6 1704448
#define CTOT 1705472

// ---------------------------------------------------------------------------
// Runtime dtype detection (unchanged).
// ---------------------------------------------------------------------------
__global__ void detect_kernel(const void* p0, const void* p1, const void* p2,
                              const void* p3, const void* p4, const void* p5,
                              const void* p6, int* flags) {
  const void* ps[7] = {p0, p1, p2, p3, p4, p5, p6};
  const int sz[7] = {SZ0, SZ1, SZ2, SZ3, SZ4, SZ5, SZ6};
  const int w = threadIdx.x >> 6;
  const int l = threadIdx.x & 63;
  if (w >= 7) return;
  const unsigned short* u = (const unsigned short*)ps[w];
  const int lim = sz[w] < 1024 ? sz[w] : 1024;
  int bad = 0;
  for (int j = l; j < lim; j += 64) {
    const unsigned e = (u[j] >> 7) & 0xFFu;
    if (e >= 0x8Eu) bad = 1;
  }
  const unsigned long long b = __ballot(bad);
  if (l == 0) flags[w] = (b != 0ULL) ? 1 : 0;
}

__global__ __launch_bounds__(256) void convert_kernel(
    const void* p0, const void* p1, const void* p2, const void* p3,
    const void* p4, const void* p5, const void* p6,
    const int* __restrict__ flags, __hip_bfloat16* __restrict__ dst) {
  const int gid = blockIdx.x * 256 + threadIdx.x;
  if (gid >= CTOT) return;
  int t, local;
  const void* p;
  if (gid < CU1)      { t = 0; local = gid - CU0; p = p0; }
  else if (gid < CU2) { t = 1; local = gid - CU1; p = p1; }
  else if (gid < CU3) { t = 2; local = gid - CU2; p = p2; }
  else if (gid < CU4) { t = 3; local = gid - CU3; p = p3; }
  else if (gid < CU5) { t = 4; local = gid - CU4; p = p4; }
  else if (gid < CU6) { t = 5; local = gid - CU5; p = p5; }
  else                { t = 6; local = gid - CU6; p = p6; }
  __hip_bfloat16 v;
  if (flags[t])
    v = __float2bfloat16(((const float*)p)[local]);
  else
    v = ((const __hip_bfloat16*)p)[local];
  dst[gid] = v;
}

// ---------------------------------------------------------------------------
// m97-structure GEMM body for the two small projections. CT (optional):
// also write the transposed result CT[col*M + row] (used for PdT).
// ---------------------------------------------------------------------------
__device__ __forceinline__ void gemm_bt_body(
    const __hip_bfloat16* __restrict__ A, const __hip_bfloat16* __restrict__ Bw,
    const __hip_bfloat16* __restrict__ bias, float* __restrict__ C,
    float* __restrict__ CT, int M, int N, int K, int bid,
    __hip_bfloat16* sA, __hip_bfloat16* sB) {
  const int tid = threadIdx.x;
  const int w = tid >> 6;
  const int l = tid & 63;
  const int ntiles = N >> 7;
  const int mt = bid / ntiles;
  const int nt = bid % ntiles;
  const int m0 = mt << 7;
  const int n0 = nt << 7;
  const int wm = (w >> 1) << 6;
  const int wn = (w & 1) << 6;
  const int r16 = l & 15;
  const int q = l >> 4;

  f32x4 acc[4][4] = {};

  const int srow_in = l >> 3;
  const int scol = (l & 7) << 3;

  for (int k0 = 0; k0 < K; k0 += 64) {
#pragma unroll
    for (int i = 0; i < 4; ++i) {
      const int c = (w << 2) + i;
      const int row = (c << 3) + srow_in;
      const __hip_bfloat16* gA = A + (size_t)(m0 + row) * K + k0 + scol;
      const __hip_bfloat16* gB = Bw + (size_t)(n0 + row) * K + k0 + scol;
      __builtin_amdgcn_global_load_lds(
          (const __attribute__((address_space(1))) void*)gA,
          (__attribute__((address_space(3))) void*)(sA + (c << 9) + (l << 3)),
          16, 0, 0);
      __builtin_amdgcn_global_load_lds(
          (const __attribute__((address_space(1))) void*)gB,
          (__attribute__((address_space(3))) void*)(sB + (c << 9) + (l << 3)),
          16, 0, 0);
    }
    __syncthreads();

#pragma unroll
    for (int kk = 0; kk < 2; ++kk) {
      const int kc = (kk << 5) + (q << 3);
      short8 af[4], bf[4];
#pragma unroll
      for (int mi = 0; mi < 4; ++mi)
        af[mi] = *(const short8*)(sA + (wm + (mi << 4) + r16) * 64 + kc);
#pragma unroll
      for (int ni = 0; ni < 4; ++ni)
        bf[ni] = *(const short8*)(sB + (wn + (ni << 4) + r16) * 64 + kc);
#pragma unroll
      for (int mi = 0; mi < 4; ++mi)
#pragma unroll
        for (int ni = 0; ni < 4; ++ni)
          acc[mi][ni] = __builtin_amdgcn_mfma_f32_16x16x32_bf16(
              af[mi], bf[ni], acc[mi][ni], 0, 0, 0);
    }
    __syncthreads();
  }

#pragma unroll
  for (int ni = 0; ni < 4; ++ni) {
    const int col = n0 + wn + (ni << 4) + r16;
    const float bc = bias ? __bfloat162float(bias[col]) : 0.0f;
#pragma unroll
    for (int mi = 0; mi < 4; ++mi) {
      const int rowb = m0 + wm + (mi << 4) + (q << 2);
#pragma unroll
      for (int i = 0; i < 4; ++i) {
        const float v = acc[mi][ni][i] + bc;
        C[(size_t)(rowb + i) * N + col] = v;
        if (CT) CT[(size_t)col * M + rowb + i] = v;
      }
    }
  }
}

// proj blocks 0..31: Pe. 32..39: Pd (+PdT transposed epilogue).
// 40..47: W_out -> WT transpose, WT[(k>>3)*1024 + n][8] (chunk-major, 1MB).
__global__ __launch_bounds__(256) void proj_kernel(
    const __hip_bfloat16* __restrict__ enc, const __hip_bfloat16* __restrict__ Wenc,
    const __hip_bfloat16* __restrict__ benc,
    const __hip_bfloat16* __restrict__ dec, const __hip_bfloat16* __restrict__ Wdec,
    const __hip_bfloat16* __restrict__ Wout, __hip_bfloat16* __restrict__ WT,
    float* __restrict__ Pe, float* __restrict__ Pd, float* __restrict__ PdT) {
  __shared__ __align__(16) __hip_bfloat16 sA[128 * 64];
  __shared__ __align__(16) __hip_bfloat16 sB[128 * 64];
  if (blockIdx.x < 32) {
    gemm_bt_body(enc, Wenc, benc, Pe, nullptr, 1024, 512, 512, blockIdx.x,
                 sA, sB);
  } else if (blockIdx.x < 40) {
    gemm_bt_body(dec, Wdec, nullptr, Pd, PdT, 256, 512, 512, blockIdx.x - 32,
                 sA, sB);
  } else {
    const int bid = blockIdx.x - 40;            // 0..7
#pragma unroll
    for (int i = 0; i < 32; ++i) {
      const int cid = (bid << 13) + (i << 8) + threadIdx.x;  // 0..65535
      const int n = cid >> 6;
      const int c = cid & 63;
      *(short8*)(WT + (((size_t)c << 10) + n) * 8) =
          *(const short8*)(Wout + (size_t)n * 512 + (c << 3));
    }
  }
}

// ---------------------------------------------------------------------------
// Main fused GEMM, m201 8-phase schedule + coalesced A via PdT.
// grid = 1024 (256 mb x 4 nb), 512 threads / 8 waves (2M x 4N),
// wave-tile 128x64, acc[4][2] f32x16, 32x32x16 MFMA.
// LDS 128KB: sA[2][8c][256r][8] + sB[2][8c][256n][8] (chunk-major).
// K = 512 = 8 K-tiles of 64; 4 phases per K-tile (one k-step of 16 each).
// Per wave per K-tile VMEM: 8 Pe f32x4 (broadcast) + 32 PdT scalar
// (256B-coalesced) + 4 B-DMA -> ~1100 lines/CU (was ~4600).
// ---------------------------------------------------------------------------
__global__ __launch_bounds__(512, 2) void gemm_joint(
    const float* __restrict__ Pe, const float* __restrict__ PdT,
    const __hip_bfloat16* __restrict__ WT,
    const __hip_bfloat16* __restrict__ bias, float* __restrict__ out) {
  __shared__ __align__(16) __hip_bfloat16 sA[2][2048 * 8];  // 2 x 32 KB
  __shared__ __align__(16) __hip_bfloat16 sB[2][2048 * 8];  // 2 x 32 KB

  const int t = threadIdx.x;
  const int w = t >> 6;
  const int l = t & 63;
  const int l31 = l & 31;
  const int q2 = l >> 5;
  const int mb = blockIdx.x >> 2;
  const int nb = blockIdx.x & 3;
  const int m0 = mb << 8;
  const int n0 = nb << 8;
  const int wm = (w >> 2) << 7;   // 0 or 128
  const int wn = (w & 3) << 6;    // 0,64,128,192

  // A-slot ownership: thread t covers row arow = t&255, chunks acb..acb+3.
  const int arow = t & 255;
  const int acb = (t >> 8) << 2;
  const int e = (mb << 2) + (arow >> 6);           // Pe row (wave-uniform)
  const int dd = ((mb >> 6) << 6) | (arow & 63);   // Pd row (= dbase + l)
  const float* pdTb = PdT + dd;                    // lane-contiguous in d

  // A-loads for tile kt, half h (chunks 2h, 2h+1). Pd via PdT: per
  // instruction 64 lanes read 256B contiguous (4 fully-used lines).
  f32x4 rPe[4][2];
  float rPd[4][8];
  auto issueA = [&](int kt, int half) {
    const float* peR = Pe + (size_t)e * 512 + (kt << 6);
#pragma unroll
    for (int jj = 0; jj < 2; ++jj) {
      const int j = (half << 1) + jj;
      const int off = (acb + j) << 3;
      rPe[j][0] = *(const f32x4*)(peR + off);
      rPe[j][1] = *(const f32x4*)(peR + off + 4);
#pragma unroll
      for (int x = 0; x < 8; ++x)
        rPd[j][x] = pdTb[(size_t)((kt << 6) + off + x) << 8];
    }
  };

  // tanh(A) -> sA[b], chunk-major, ds_write lane-consecutive 16B.
  auto writeA = [&](int b) {
#pragma unroll
    for (int j = 0; j < 4; ++j) {
      short8 hv;
#pragma unroll
      for (int x = 0; x < 4; ++x) {
        float sv = rPe[j][0][x] + rPd[j][x];
        float u = __expf(2.0f * sv);
        float tv = 1.0f - 2.0f * __builtin_amdgcn_rcpf(u + 1.0f);
        __hip_bfloat16 hb = __float2bfloat16(tv);
        hv[x] = *(const short*)&hb;
        sv = rPe[j][1][x] + rPd[j][x + 4];
        u = __expf(2.0f * sv);
        tv = 1.0f - 2.0f * __builtin_amdgcn_rcpf(u + 1.0f);
        hb = __float2bfloat16(tv);
        hv[4 + x] = *(const short*)&hb;
      }
      *(short8*)(&sA[b][0] + ((((acb + j) << 8) + arow) << 3)) = hv;
    }
  };

  // One B-DMA instruction: slot = h*512+t; c = slot>>8, n = slot&255.
  // WT source: 64 consecutive lanes = 1KB contiguous. Dest uniform+l*16.
  auto issueB = [&](int kt, int b, int h) {
    const int slot = (h << 9) + t;
    const int c = slot >> 8;
    const int n = slot & 255;
    const __hip_bfloat16* src =
        WT + (((size_t)((kt << 3) + c) << 10) + n0 + n) * 8;
    __builtin_amdgcn_global_load_lds(
        (const __attribute__((address_space(1))) void*)src,
        (__attribute__((address_space(3))) void*)(&sB[b][0] + (slot << 3)),
        16, 0, 0);
  };

  // Prologue: tile 0 fully staged (A regs -> tanh -> LDS; B via DMA).
  issueA(0, 0);
  issueA(0, 1);
#pragma unroll
  for (int h = 0; h < 4; ++h) issueB(0, 0, h);
  asm volatile("s_waitcnt vmcnt(4)" ::: "memory");   // A-loads done
  __builtin_amdgcn_sched_barrier(0);
  writeA(0);
  asm volatile("s_waitcnt lgkmcnt(0) vmcnt(0)" ::: "memory");
  __builtin_amdgcn_sched_barrier(0);
  __builtin_amdgcn_s_barrier();
  __builtin_amdgcn_sched_barrier(0);

  f32x16 acc[4][2] = {};

#define READS(s)                                                             \
  {                                                                          \
    const int c = ((s) << 1) + q2;                                           \
    _Pragma("unroll") for (int mi = 0; mi < 4; ++mi) af[mi] =                \
        *(const short8*)(&sA[b][0] +                                         \
                         (((c << 8) + wm + (mi << 5) + l31) << 3));          \
    _Pragma("unroll") for (int ni = 0; ni < 2; ++ni) bf[ni] =                \
        *(const short8*)(&sB[b][0] +                                         \
                         (((c << 8) + wn + (ni << 5) + l31) << 3));          \
  }
#define MFMA8                                                                \
  _Pragma("unroll") for (int mi = 0; mi < 4; ++mi)                           \
      _Pragma("unroll") for (int ni = 0; ni < 2; ++ni) acc[mi][ni] =         \
          __builtin_amdgcn_mfma_f32_32x32x16_bf16(af[mi], bf[ni],            \
                                                  acc[mi][ni], 0, 0, 0);
#define PHASE_SYNC_PRE                                                       \
  __builtin_amdgcn_s_barrier();                                              \
  asm volatile("s_waitcnt lgkmcnt(0)" ::: "memory");                         \
  __builtin_amdgcn_sched_barrier(0);                                         \
  __builtin_amdgcn_s_setprio(1);
#define PHASE_SYNC_POST                                                      \
  __builtin_amdgcn_s_setprio(0);                                             \
  __builtin_amdgcn_sched_barrier(0);                                         \
  __builtin_amdgcn_s_barrier();                                              \
  __builtin_amdgcn_sched_barrier(0);

#pragma unroll
  for (int kt = 0; kt < 8; ++kt) {
    const int b = kt & 1;
    short8 af[4], bf[2];

    // ---- phase 0: issue next tile's A-loads (half 0); k-step 0
    if (kt < 7) issueA(kt + 1, 0);
    READS(0)
    PHASE_SYNC_PRE
    MFMA8
    PHASE_SYNC_POST

    // ---- phase 1: issue next tile's A-loads (half 1); k-step 1
    if (kt < 7) issueA(kt + 1, 1);
    READS(1)
    PHASE_SYNC_PRE
    MFMA8
    PHASE_SYNC_POST

    // ---- phase 2: issue all 4 B-DMAs; k-step 2
    if (kt < 7) {
      issueB(kt + 1, b ^ 1, 0); issueB(kt + 1, b ^ 1, 1);
      issueB(kt + 1, b ^ 1, 2); issueB(kt + 1, b ^ 1, 3);
    }
    READS(2)
    PHASE_SYNC_PRE
    MFMA8
    PHASE_SYNC_POST

    // ---- phase 3: k-step 3 + tanh->ds_write(b^1) + counted drains
    READS(3)
    if (kt < 7) {
      asm volatile("s_waitcnt vmcnt(4)" ::: "memory");  // A-loads done,
      __builtin_amdgcn_sched_barrier(0);                // 4 B-DMAs in flight
      writeA(b ^ 1);
    }
    __builtin_amdgcn_s_barrier();
    asm volatile("s_waitcnt lgkmcnt(0)" ::: "memory");  // reads + A-writes
    __builtin_amdgcn_sched_barrier(0);
    __builtin_amdgcn_s_setprio(1);
    MFMA8
    __builtin_amdgcn_s_setprio(0);
    asm volatile("s_waitcnt vmcnt(0)" ::: "memory");    // B(kt+1) landed
    __builtin_amdgcn_sched_barrier(0);
    __builtin_amdgcn_s_barrier();   // publish b^1 (A writes + B DMA) to all
    __builtin_amdgcn_sched_barrier(0);
  }
#undef READS
#undef MFMA8
#undef PHASE_SYNC_PRE
#undef PHASE_SYNC_POST

  // Epilogue: C/D layout (harness-verified R4..R12):
  // col = l&31, row = (rr&3) + 8*(rr>>2) + 4*q2.
#pragma unroll
  for (int ni = 0; ni < 2; ++ni) {
    const int col = n0 + wn + (ni << 5) + l31;
    const float bc = __bfloat162float(bias[col]);
#pragma unroll
    for (int mi = 0; mi < 4; ++mi) {
#pragma unroll
      for (int rr = 0; rr < 16; ++rr) {
        const int row = m0 + wm + (mi << 5) + (rr & 3) + ((rr >> 2) << 3) +
                        (q2 << 2);
        out[(size_t)row * 1024 + col] = acc[mi][ni][rr] + bc;
      }
    }
  }
}

// ---------------------------------------------------------------------------
extern "C" void kernel_launch(void* const* d_in, const int* in_sizes, int n_in,
                              void* d_out, int out_size, void* d_ws,
                              size_t ws_size, hipStream_t stream) {
  // ws: 0 flags | 256 bf16 copies (3.41MB) | 4MB Pe (2MB) | 6MB Pd (0.5MB)
  //     | 8MB WT (1MB) | 9MB PdT (0.5MB, k-major fp32 transpose of Pd)
  char* ws = (char*)d_ws;
  int* flags = (int*)ws;
  __hip_bfloat16* cp = (__hip_bfloat16*)(ws + 256);
  float* Pe = (float*)(ws + (4ull << 20));
  float* Pd = (float*)(ws + (6ull << 20));
  __hip_bfloat16* WT = (__hip_bfloat16*)(ws + (8ull << 20));
  float* PdT = (float*)(ws + (9ull << 20));

  detect_kernel<<<dim3(1), dim3(512), 0, stream>>>(
      d_in[0], d_in[1], d_in[2], d_in[3], d_in[4], d_in[5], d_in[6], flags);
  convert_kernel<<<dim3((CTOT + 255) / 256), dim3(256), 0, stream>>>(
      d_in[0], d_in[1], d_in[2], d_in[3], d_in[4], d_in[5], d_in[6], flags, cp);

  const __hip_bfloat16* enc_c = cp + CU0;
  const __hip_bfloat16* dec_c = cp + CU1;
  const __hip_bfloat16* Wenc_c = cp + CU2;
  const __hip_bfloat16* benc_c = cp + CU3;
  const __hip_bfloat16* Wdec_c = cp + CU4;
  const __hip_bfloat16* Wout_c = cp + CU5;
  const __hip_bfloat16* bout_c = cp + CU6;

  proj_kernel<<<dim3(48), dim3(256), 0, stream>>>(
      enc_c, Wenc_c, benc_c, dec_c, Wdec_c, Wout_c, WT, Pe, Pd, PdT);
  gemm_joint<<<dim3(1024), dim3(512), 0, stream>>>(
      Pe, PdT, WT, bout_c, (float*)d_out);
}

// Round 14
// 387.564 us; speedup vs baseline: 1.1249x; 1.0492x over previous
//
#include <hip/hip_runtime.h>
#include <hip/hip_bf16.h>

// RNN-T joint network. B=4 T=256 U=64 D=512 J=512 V=1024.
//   Pe = enc @ W_enc^T + b_enc   (1024 x 512)  fp32 in ws
//   Pd = dec @ W_dec^T           (256  x 512)  fp32 in ws (+ PdT k-major)
//   out[m,:] = tanh(Pe[m>>6] + Pd[(m>>14)*64 + (m&63)]) @ W_out^T + b_out
//
// Round-14 = R10 (best measured base, 393us total) + R13's gather fix.
//   R10-R13 findings: (1) R10's 2-phase / 2WG/CU / BK=32 structure beats
//   the 8-phase port on this problem; (2) the Pd A-production gather costs
//   ~30us (R12->R13 measured). R10 still had the gather in fillH (f32x8
//   per-lane reads of 2KB-strided rows = 4x wasted L1 lines). This round
//   combines them: fillH reads PdT[k][256d] -- lane-contiguous in d, each
//   scalar wave-instr = 256B contiguous (4 fully-used lines).
// Geometry (R10, unchanged): BM=128, BN=256 (nb=4), BK=32, 2048 blocks,
// 512 thr / 8 waves, wave-tile 64x64, acc[2][2] f32x16, 2 WG/CU
// (LDS 64KB: sH 32KB quarter-K + sB dbuf 2x16KB, chunk-major, 0-conflict),
// counted vmcnt(2), raw-barrier pair per kt, fillH at quarter boundaries.

typedef __attribute__((ext_vector_type(8))) short short8;     // 8 bf16
typedef __attribute__((ext_vector_type(4))) float f32x4;
typedef __attribute__((ext_vector_type(8))) float f32x8;
typedef __attribute__((ext_vector_type(16))) float f32x16;

#define SZ0 524288
#define SZ1 131072
#define SZ2 262144
#define SZ3 512
#define SZ4 262144
#define SZ5 524288
#define SZ6 1024
#define CU0 0
#define CU1 524288
#define CU2 655360
#define CU3 917504
#define CU4 918016
#define CU5 1180160
#define CU6 1704448
#define CTOT 1705472

// ---------------------------------------------------------------------------
// Runtime dtype detection (unchanged).
// ---------------------------------------------------------------------------
__global__ void detect_kernel(const void* p0, const void* p1, const void* p2,
                              const void* p3, const void* p4, const void* p5,
                              const void* p6, int* flags) {
  const void* ps[7] = {p0, p1, p2, p3, p4, p5, p6};
  const int sz[7] = {SZ0, SZ1, SZ2, SZ3, SZ4, SZ5, SZ6};
  const int w = threadIdx.x >> 6;
  const int l = threadIdx.x & 63;
  if (w >= 7) return;
  const unsigned short* u = (const unsigned short*)ps[w];
  const int lim = sz[w] < 1024 ? sz[w] : 1024;
  int bad = 0;
  for (int j = l; j < lim; j += 64) {
    const unsigned e = (u[j] >> 7) & 0xFFu;
    if (e >= 0x8Eu) bad = 1;
  }
  const unsigned long long b = __ballot(bad);
  if (l == 0) flags[w] = (b != 0ULL) ? 1 : 0;
}

__global__ __launch_bounds__(256) void convert_kernel(
    const void* p0, const void* p1, const void* p2, const void* p3,
    const void* p4, const void* p5, const void* p6,
    const int* __restrict__ flags, __hip_bfloat16* __restrict__ dst) {
  const int gid = blockIdx.x * 256 + threadIdx.x;
  if (gid >= CTOT) return;
  int t, local;
  const void* p;
  if (gid < CU1)      { t = 0; local = gid - CU0; p = p0; }
  else if (gid < CU2) { t = 1; local = gid - CU1; p = p1; }
  else if (gid < CU3) { t = 2; local = gid - CU2; p = p2; }
  else if (gid < CU4) { t = 3; local = gid - CU3; p = p3; }
  else if (gid < CU5) { t = 4; local = gid - CU4; p = p4; }
  else if (gid < CU6) { t = 5; local = gid - CU5; p = p5; }
  else                { t = 6; local = gid - CU6; p = p6; }
  __hip_bfloat16 v;
  if (flags[t])
    v = __float2bfloat16(((const float*)p)[local]);
  else
    v = ((const __hip_bfloat16*)p)[local];
  dst[gid] = v;
}

// ---------------------------------------------------------------------------
// m97-structure GEMM body for the two small projections. CT (optional):
// also write the transposed result CT[col*M + row] (used for PdT).
// ---------------------------------------------------------------------------
__device__ __forceinline__ void gemm_bt_body(
    const __hip_bfloat16* __restrict__ A, const __hip_bfloat16* __restrict__ Bw,
    const __hip_bfloat16* __restrict__ bias, float* __restrict__ C,
    float* __restrict__ CT, int M, int N, int K, int bid,
    __hip_bfloat16* sA, __hip_bfloat16* sB) {
  const int tid = threadIdx.x;
  const int w = tid >> 6;
  const int l = tid & 63;
  const int ntiles = N >> 7;
  const int mt = bid / ntiles;
  const int nt = bid % ntiles;
  const int m0 = mt << 7;
  const int n0 = nt << 7;
  const int wm = (w >> 1) << 6;
  const int wn = (w & 1) << 6;
  const int r16 = l & 15;
  const int q = l >> 4;

  f32x4 acc[4][4] = {};

  const int srow_in = l >> 3;
  const int scol = (l & 7) << 3;

  for (int k0 = 0; k0 < K; k0 += 64) {
#pragma unroll
    for (int i = 0; i < 4; ++i) {
      const int c = (w << 2) + i;
      const int row = (c << 3) + srow_in;
      const __hip_bfloat16* gA = A + (size_t)(m0 + row) * K + k0 + scol;
      const __hip_bfloat16* gB = Bw + (size_t)(n0 + row) * K + k0 + scol;
      __builtin_amdgcn_global_load_lds(
          (const __attribute__((address_space(1))) void*)gA,
          (__attribute__((address_space(3))) void*)(sA + (c << 9) + (l << 3)),
          16, 0, 0);
      __builtin_amdgcn_global_load_lds(
          (const __attribute__((address_space(1))) void*)gB,
          (__attribute__((address_space(3))) void*)(sB + (c << 9) + (l << 3)),
          16, 0, 0);
    }
    __syncthreads();

#pragma unroll
    for (int kk = 0; kk < 2; ++kk) {
      const int kc = (kk << 5) + (q << 3);
      short8 af[4], bf[4];
#pragma unroll
      for (int mi = 0; mi < 4; ++mi)
        af[mi] = *(const short8*)(sA + (wm + (mi << 4) + r16) * 64 + kc);
#pragma unroll
      for (int ni = 0; ni < 4; ++ni)
        bf[ni] = *(const short8*)(sB + (wn + (ni << 4) + r16) * 64 + kc);
#pragma unroll
      for (int mi = 0; mi < 4; ++mi)
#pragma unroll
        for (int ni = 0; ni < 4; ++ni)
          acc[mi][ni] = __builtin_amdgcn_mfma_f32_16x16x32_bf16(
              af[mi], bf[ni], acc[mi][ni], 0, 0, 0);
    }
    __syncthreads();
  }

#pragma unroll
  for (int ni = 0; ni < 4; ++ni) {
    const int col = n0 + wn + (ni << 4) + r16;
    const float bc = bias ? __bfloat162float(bias[col]) : 0.0f;
#pragma unroll
    for (int mi = 0; mi < 4; ++mi) {
      const int rowb = m0 + wm + (mi << 4) + (q << 2);
#pragma unroll
      for (int i = 0; i < 4; ++i) {
        const float v = acc[mi][ni][i] + bc;
        C[(size_t)(rowb + i) * N + col] = v;
        if (CT) CT[(size_t)col * M + rowb + i] = v;
      }
    }
  }
}

// proj blocks 0..31: Pe. 32..39: Pd (+PdT k-major epilogue).
// 40..47: W_out -> WT transpose, WT[(k>>3)*1024 + n][8] (chunk-major, 1MB).
__global__ __launch_bounds__(256) void proj_kernel(
    const __hip_bfloat16* __restrict__ enc, const __hip_bfloat16* __restrict__ Wenc,
    const __hip_bfloat16* __restrict__ benc,
    const __hip_bfloat16* __restrict__ dec, const __hip_bfloat16* __restrict__ Wdec,
    const __hip_bfloat16* __restrict__ Wout, __hip_bfloat16* __restrict__ WT,
    float* __restrict__ Pe, float* __restrict__ Pd, float* __restrict__ PdT) {
  __shared__ __align__(16) __hip_bfloat16 sA[128 * 64];
  __shared__ __align__(16) __hip_bfloat16 sB[128 * 64];
  if (blockIdx.x < 32) {
    gemm_bt_body(enc, Wenc, benc, Pe, nullptr, 1024, 512, 512, blockIdx.x,
                 sA, sB);
  } else if (blockIdx.x < 40) {
    gemm_bt_body(dec, Wdec, nullptr, Pd, PdT, 256, 512, 512, blockIdx.x - 32,
                 sA, sB);
  } else {
    const int bid = blockIdx.x - 40;            // 0..7
#pragma unroll
    for (int i = 0; i < 32; ++i) {
      const int cid = (bid << 13) + (i << 8) + threadIdx.x;  // 0..65535
      const int n = cid >> 6;
      const int c = cid & 63;
      *(short8*)(WT + (((size_t)c << 10) + n) * 8) =
          *(const short8*)(Wout + (size_t)n * 512 + (c << 3));
    }
  }
}

// ---------------------------------------------------------------------------
// Main fused GEMM (R10 structure). grid = 2048 blocks (512 mb x 4 nb),
// 512 threads (8 waves), 2 WG/CU (64KB LDS, <=128 VGPR).
// Wave grid 2(M)x4(N): wave-tile 64x64, acc[2][2] f32x16. 16 tile-iters
// (BK=32), 2 sub-steps each. Per iter/thread: 2 gload_lds (stage next from
// WT, contiguous), 8 ds_read, 8 MFMA, counted vmcnt(2), 2 raw barriers.
// sH refilled at kt=4,8,12; fillH Pd reads via PdT (256B-coalesced).
// ---------------------------------------------------------------------------
__global__ __launch_bounds__(512, 4) void gemm_joint(
    const float* __restrict__ Pe, const float* __restrict__ PdT,
    const __hip_bfloat16* __restrict__ WT,
    const __hip_bfloat16* __restrict__ bias, float* __restrict__ out) {
  __shared__ __align__(16) __hip_bfloat16 sH[16 * 128 * 8];     // 32 KB
  __shared__ __align__(16) __hip_bfloat16 sB[2][4 * 256 * 8];   // 2 x 16 KB

  const int t = threadIdx.x;
  const int w = t >> 6;
  const int l = t & 63;
  const int l31 = l & 31;
  const int q2 = l >> 5;
  const int mb = blockIdx.x >> 2;
  const int nb = blockIdx.x & 3;
  const int m0 = mb << 7;
  const int n0 = nb << 8;

  // STAGE: sB[b] <- WT k-chunks [kt*4 .. kt*4+4) x cols [n0, n0+256).
  auto stage = [&](int kt, int b) {
#pragma unroll
    for (int h = 0; h < 2; ++h) {
      const int slot = (h << 9) + t;
      const int kq = slot >> 8;
      const int n = slot & 255;
      const __hip_bfloat16* src =
          WT + (((size_t)((kt << 2) + kq) << 10) + n0 + n) * 8;
      __builtin_amdgcn_global_load_lds(
          (const __attribute__((address_space(1))) void*)src,
          (__attribute__((address_space(3))) void*)(&sB[b][0] + (slot << 3)),
          16, 0, 0);
    }
  };

  // FILL: sH[cq][r][8] = tanh(Pe[e][q*128+cq*8+..] + Pd[d][...]), quarter q.
  // Pe: wave-uniform broadcast. Pd via PdT[k][256d]: lane-contiguous in d
  // (r = t&127 -> consecutive lanes = consecutive d), each scalar
  // wave-instruction reads 256B contiguous = 4 fully-used cache lines
  // (R10's f32x8 row-gather touched 4x the lines at 25% utilization).
  auto fillH = [&](int q) {
    const int r = t & 127;
    const int e = (mb << 1) + (r >> 6);
    const float* peR = Pe + (size_t)e * 512 + (q << 7);
    const float* pdTb = PdT + ((mb >> 7) << 6) + (r & 63);
#pragma unroll
    for (int s2 = 0; s2 < 4; ++s2) {
      const int cq = (s2 << 2) + (t >> 7);   // 0..15
      const f32x8 a = *(const f32x8*)(peR + (cq << 3));
      float pd[8];
#pragma unroll
      for (int x = 0; x < 8; ++x)
        pd[x] = pdTb[(size_t)((q << 7) + (cq << 3) + x) << 8];
      short8 hv;
#pragma unroll
      for (int x = 0; x < 8; ++x) {
        const float sv = a[x] + pd[x];
        const float u = __expf(2.0f * sv);
        const float tv = 1.0f - 2.0f * __builtin_amdgcn_rcpf(u + 1.0f);
        const __hip_bfloat16 hb = __float2bfloat16(tv);
        hv[x] = *(const short*)&hb;
      }
      *(short8*)(sH + ((size_t)((cq << 7) + r) << 3)) = hv;
    }
  };

  stage(0, 0);
  fillH(0);
  __syncthreads();   // full drain once: stage(0) DMA + sH writes

  const int wm = (w >> 2) << 6;   // 0 or 64 (M)
  const int wn = (w & 3) << 6;    // 0,64,128,192 (N)
  f32x16 acc[2][2] = {};

  for (int kt = 0; kt < 16; ++kt) {
    const int b = kt & 1;
    if (kt < 15) {
      stage(kt + 1, b ^ 1);
      asm volatile("s_waitcnt vmcnt(2)" ::: "memory");  // stage(kt) landed
    } else {
      asm volatile("s_waitcnt vmcnt(0)" ::: "memory");
    }
    __builtin_amdgcn_sched_barrier(0);
    __builtin_amdgcn_s_barrier();        // barrier A: sB[b] ready for all
    __builtin_amdgcn_sched_barrier(0);

    if ((kt & 3) == 0 && kt) {
      // Quarter boundary: refill sH (prev quarter's readers finished at
      // the previous end-barrier). lgkmcnt(0) before barrier: ds_writes
      // complete before any wave reads.
      fillH(kt >> 2);
      asm volatile("s_waitcnt lgkmcnt(0)" ::: "memory");
      __builtin_amdgcn_sched_barrier(0);
      __builtin_amdgcn_s_barrier();
      __builtin_amdgcn_sched_barrier(0);
    }

#pragma unroll
    for (int ss = 0; ss < 2; ++ss) {
      const int kq = (ss << 1) + q2;                  // sB k-chunk
      const int cq = ((kt & 3) << 2) + kq;            // sH k-chunk in quarter
      short8 af[2], bf[2];
#pragma unroll
      for (int mi = 0; mi < 2; ++mi)
        af[mi] = *(const short8*)(sH +
                                  (((cq << 7) + wm + (mi << 5) + l31) << 3));
#pragma unroll
      for (int ni = 0; ni < 2; ++ni)
        bf[ni] = *(const short8*)(&sB[b][0] +
                                  (((kq << 8) + wn + (ni << 5) + l31) << 3));
#pragma unroll
      for (int mi = 0; mi < 2; ++mi)
#pragma unroll
        for (int ni = 0; ni < 2; ++ni)
          acc[mi][ni] = __builtin_amdgcn_mfma_f32_32x32x16_bf16(
              af[mi], bf[ni], acc[mi][ni], 0, 0, 0);
    }

    __builtin_amdgcn_sched_barrier(0);
    __builtin_amdgcn_s_barrier();        // barrier C: sB[b] readers done
    __builtin_amdgcn_sched_barrier(0);
  }

  // Epilogue: C/D layout (harness-verified R4..R13):
  // col = l&31, row = (rr&3) + 8*(rr>>2) + 4*q2.
#pragma unroll
  for (int ni = 0; ni < 2; ++ni) {
    const int col = n0 + wn + (ni << 5) + l31;
    const float bc = __bfloat162float(bias[col]);
#pragma unroll
    for (int mi = 0; mi < 2; ++mi) {
#pragma unroll
      for (int rr = 0; rr < 16; ++rr) {
        const int row = m0 + wm + (mi << 5) + (rr & 3) + ((rr >> 2) << 3) +
                        (q2 << 2);
        out[(size_t)row * 1024 + col] = acc[mi][ni][rr] + bc;
      }
    }
  }
}

// ---------------------------------------------------------------------------
extern "C" void kernel_launch(void* const* d_in, const int* in_sizes, int n_in,
                              void* d_out, int out_size, void* d_ws,
                              size_t ws_size, hipStream_t stream) {
  // ws: 0 flags | 256 bf16 copies (3.41MB) | 4MB Pe (2MB) | 6MB Pd (0.5MB)
  //     | 8MB WT (1MB) | 9MB PdT (0.5MB, k-major fp32 transpose of Pd)
  char* ws = (char*)d_ws;
  int* flags = (int*)ws;
  __hip_bfloat16* cp = (__hip_bfloat16*)(ws + 256);
  float* Pe = (float*)(ws + (4ull << 20));
  float* Pd = (float*)(ws + (6ull << 20));
  __hip_bfloat16* WT = (__hip_bfloat16*)(ws + (8ull << 20));
  float* PdT = (float*)(ws + (9ull << 20));

  detect_kernel<<<dim3(1), dim3(512), 0, stream>>>(
      d_in[0], d_in[1], d_in[2], d_in[3], d_in[4], d_in[5], d_in[6], flags);
  convert_kernel<<<dim3((CTOT + 255) / 256), dim3(256), 0, stream>>>(
      d_in[0], d_in[1], d_in[2], d_in[3], d_in[4], d_in[5], d_in[6], flags, cp);

  const __hip_bfloat16* enc_c = cp + CU0;
  const __hip_bfloat16* dec_c = cp + CU1;
  const __hip_bfloat16* Wenc_c = cp + CU2;
  const __hip_bfloat16* benc_c = cp + CU3;
  const __hip_bfloat16* Wdec_c = cp + CU4;
  const __hip_bfloat16* Wout_c = cp + CU5;
  const __hip_bfloat16* bout_c = cp + CU6;

  proj_kernel<<<dim3(48), dim3(256), 0, stream>>>(
      enc_c, Wenc_c, benc_c, dec_c, Wdec_c, Wout_c, WT, Pe, Pd, PdT);
  gemm_joint<<<dim3(2048), dim3(512), 0, stream>>>(
      Pe, PdT, WT, bout_c, (float*)d_out);
}